// Round 1
// baseline (2475.607 us; speedup 1.0000x reference)
//
#include <hip/hip_runtime.h>

#define NN 50000
#define NE 400000
#define DIM 128

typedef __bf16 bf16x8 __attribute__((ext_vector_type(8)));
typedef float f32x4 __attribute__((ext_vector_type(4)));
typedef unsigned short u16;

#define MFMA16 __builtin_amdgcn_mfma_f32_16x16x32_bf16

__device__ __forceinline__ u16 f2b(float f){ __bf16 b=(__bf16)f; return __builtin_bit_cast(u16,b); }
__device__ __forceinline__ float sigm(float x){ return 1.0f/(1.0f+__expf(-x)); }
__device__ __forceinline__ float tanh_(float x){ float e=__expf(2.0f*x); return 1.0f-2.0f/(e+1.0f); }
__device__ __forceinline__ bf16x8 ldb8(const u16* p){ return *reinterpret_cast<const bf16x8*>(p); }

// ---------- utility kernels ----------
__global__ void f2b_kernel(const float* __restrict__ in, u16* __restrict__ out, int n4){
  int i = blockIdx.x*blockDim.x + threadIdx.x;
  int st = gridDim.x*blockDim.x;
  for (; i<n4; i+=st){
    float4 v = reinterpret_cast<const float4*>(in)[i];
    ushort4 o = { f2b(v.x), f2b(v.y), f2b(v.z), f2b(v.w) };
    reinterpret_cast<ushort4*>(out)[i] = o;
  }
}

__global__ void transpose128_kernel(const float* __restrict__ in, u16* __restrict__ out){
  int i = blockIdx.x*blockDim.x + threadIdx.x; // 16384 threads total
  int k = i>>7, n = i&127;
  out[n*128+k] = f2b(in[i]);   // out[n][k] = in[k][n]
}

__global__ void zero_kernel(int* p, int n){
  int i = blockIdx.x*blockDim.x + threadIdx.x; if (i<n) p[i]=0;
}
__global__ void hist_kernel(const int* __restrict__ dst, int* __restrict__ counts, int n){
  int i = blockIdx.x*blockDim.x + threadIdx.x; if (i<n) atomicAdd(&counts[dst[i]],1);
}
__global__ void scan_kernel(const int* __restrict__ counts, int* __restrict__ rowp,
                            int* __restrict__ cursor, int n){
  __shared__ int buf[1024];
  __shared__ int run;
  const int t = threadIdx.x;
  if (t==0) run = 0;
  __syncthreads();
  for (int base=0; base<n; base+=1024){
    int v = (base+t<n) ? counts[base+t] : 0;
    buf[t]=v; __syncthreads();
    for (int off=1; off<1024; off<<=1){
      int x = (t>=off) ? buf[t-off] : 0;
      __syncthreads();
      buf[t]+=x; __syncthreads();
    }
    int incl = buf[t];
    int br = run;
    __syncthreads();
    if (base+t<n){ int ex = br+incl-v; rowp[base+t]=ex; cursor[base+t]=ex; }
    if (t==1023) run = br+incl;
    __syncthreads();
  }
  if (t==0) rowp[n]=run;
}
__global__ void scatter_kernel(const int* __restrict__ dst, int* __restrict__ cursor,
                               int* __restrict__ eids, int n){
  int i = blockIdx.x*blockDim.x + threadIdx.x;
  if (i<n){ int p = atomicAdd(&cursor[dst[i]],1); eids[p]=i; }
}

// ---------- edge GRU + attention MLP ----------
// WG = 256 threads = 4 waves, 64 edges per WG. Wave w owns output chunks c = 2w, 2w+1.
// MFMA frag model: A lane holds A[row=l&15][k = 8*(l>>4)+j] (8 contiguous bf16);
// B (weights stored [N][K] row-major) lane holds W[col=l&15][same k];
// C/D: col = l&15, row = (l>>4)*4 + reg   [verified layout, learn_hip m89].
__global__ __launch_bounds__(256)
void edge_kernel(const int* __restrict__ src, const int* __restrict__ dst,
                 const u16* __restrict__ nfb, u16* __restrict__ efb,
                 const float* ef32, float* uef32,            // may alias (in-place iter 2)
                 const u16* __restrict__ Wih, const u16* __restrict__ Whh,
                 const float* __restrict__ bih, const float* __restrict__ bhh,
                 const u16* __restrict__ aW1T, const float* __restrict__ ab1,
                 const float* __restrict__ aW2, const float* __restrict__ ab2,
                 float* __restrict__ logits)
{
  __shared__ __align__(16) u16 u_lds[64*DIM];   // 16 KB: WG's uef tile in bf16
  const int wave = threadIdx.x>>6, lane = threadIdx.x&63;
  const int r16 = lane&15, kq = lane>>4;
  const long base = (long)blockIdx.x*64;

  const u16 *sA[4], *dA[4], *eA[4];
#pragma unroll
  for (int m=0;m<4;++m){
    long e = base + m*16 + r16;
    sA[m] = nfb + (long)src[e]*DIM;
    dA[m] = nfb + (long)dst[e]*DIM;
    eA[m] = efb + e*DIM;
  }

  const f32x4 vzero = {0.f,0.f,0.f,0.f};

#pragma unroll 1
  for (int ci=0; ci<2; ++ci){
    const int c = wave*2 + ci;
    f32x4 ar[4],az[4],an[4],hr[4],hz[4],hn[4];
#pragma unroll
    for (int m=0;m<4;++m){ ar[m]=vzero; az[m]=vzero; an[m]=vzero; hr[m]=vzero; hz[m]=vzero; hn[m]=vzero; }

    // gi = [nf[src];nf[dst]] @ eW_ih^T   (K=256; s<4 -> src half, s>=4 -> dst half)
    const u16* wr = Wih + (long)(c*16+r16)*256 + kq*8;
#pragma unroll
    for (int s=0;s<8;++s){
      const int k = s*32;
      bf16x8 b0 = ldb8(wr+k);
      bf16x8 b1 = ldb8(wr+k+128*256);
      bf16x8 b2 = ldb8(wr+k+256*256);
      const int ak = k + kq*8;
#pragma unroll
      for (int m=0;m<4;++m){
        bf16x8 a = ldb8( s<4 ? sA[m]+ak : dA[m]+(ak-DIM) );
        ar[m]=MFMA16(a,b0,ar[m],0,0,0);
        az[m]=MFMA16(a,b1,az[m],0,0,0);
        an[m]=MFMA16(a,b2,an[m],0,0,0);
      }
    }
    // gh = ef @ eW_hh^T   (K=128)
    const u16* vr = Whh + (long)(c*16+r16)*128 + kq*8;
#pragma unroll
    for (int s=0;s<4;++s){
      const int k = s*32;
      bf16x8 b0 = ldb8(vr+k);
      bf16x8 b1 = ldb8(vr+k+128*128);
      bf16x8 b2 = ldb8(vr+k+256*128);
#pragma unroll
      for (int m=0;m<4;++m){
        bf16x8 a = ldb8(eA[m]+k+kq*8);
        hr[m]=MFMA16(a,b0,hr[m],0,0,0);
        hz[m]=MFMA16(a,b1,hz[m],0,0,0);
        hn[m]=MFMA16(a,b2,hn[m],0,0,0);
      }
    }
    // gates
    const int oc = c*16 + r16;
    const float bir=bih[oc], biz=bih[DIM+oc], bin=bih[2*DIM+oc];
    const float bhr=bhh[oc], bhz=bhh[DIM+oc], bhn=bhh[2*DIM+oc];
#pragma unroll
    for (int m=0;m<4;++m){
#pragma unroll
      for (int r=0;r<4;++r){
        const long ee = base + m*16 + kq*4 + r;
        float rg = sigm(ar[m][r]+bir + hr[m][r]+bhr);
        float zg = sigm(az[m][r]+biz + hz[m][r]+bhz);
        float ng = tanh_(an[m][r]+bin + rg*(hn[m][r]+bhn));
        float h0 = ef32[ee*DIM+oc];
        float u  = (1.0f-zg)*ng + zg*h0;
        uef32[ee*DIM+oc] = u;
        u_lds[(m*16+kq*4+r)*DIM+oc] = f2b(u);
      }
    }
  }
  __syncthreads();  // all efb reads done; uef tile complete in LDS

  // attention MLP: wave w handles M-tile w (16 edges)
  const u16* myu = u_lds + wave*16*DIM;
  bf16x8 ua[4];
#pragma unroll
  for (int s=0;s<4;++s) ua[s] = ldb8(myu + r16*DIM + s*32 + kq*8);
  float part[4] = {0.f,0.f,0.f,0.f};
#pragma unroll 1
  for (int t=0;t<8;++t){
    f32x4 h = vzero;
#pragma unroll
    for (int s=0;s<4;++s)
      h = MFMA16(ua[s], ldb8(aW1T + (long)(t*16+r16)*128 + s*32 + kq*8), h,0,0,0);
    const int cc = t*16 + r16;
    const float b1 = ab1[cc], w2 = aW2[cc];
#pragma unroll
    for (int r=0;r<4;++r) part[r] += fmaxf(h[r]+b1, 0.f)*w2;
  }
#pragma unroll
  for (int off=1; off<16; off<<=1){
#pragma unroll
    for (int r=0;r<4;++r) part[r] += __shfl_xor(part[r], off, 64);
  }
  if (r16==0){
    const float b2 = ab2[0];
#pragma unroll
    for (int r=0;r<4;++r) logits[base + wave*16 + kq*4 + r] = part[r] + b2;
  }
  // write bf16 uef tile back to efb (in place: all reads happened before the barrier)
  const uint4* spv = reinterpret_cast<const uint4*>(u_lds);
  uint4* dpv = reinterpret_cast<uint4*>(efb + base*DIM);
#pragma unroll
  for (int i=0;i<4;++i) dpv[threadIdx.x + 256*i] = spv[threadIdx.x + 256*i];
}

// ---------- softmax + weighted aggregation (CSR, one wave per node) ----------
__global__ __launch_bounds__(256)
void agg_kernel(const int* __restrict__ rowp, const int* __restrict__ eids,
                const float* __restrict__ logits, const float* __restrict__ uef,
                u16* __restrict__ aggb)
{
  const int wave = threadIdx.x>>6, lane = threadIdx.x&63;
  const int v = blockIdx.x*4 + wave;
  if (v>=NN) return;
  const int p0 = rowp[v], p1 = rowp[v+1], deg = p1-p0;
  float ax=0.f, ay=0.f;
  if (deg>0){
    float mx = -__builtin_inff();
    for (int i=lane; i<deg; i+=64) mx = fmaxf(mx, logits[eids[p0+i]]);
#pragma unroll
    for (int off=32; off; off>>=1) mx = fmaxf(mx, __shfl_xor(mx, off, 64));
    float ss = 0.f;
    for (int i=lane; i<deg; i+=64) ss += __expf(logits[eids[p0+i]] - mx);
#pragma unroll
    for (int off=32; off; off>>=1) ss += __shfl_xor(ss, off, 64);
    const float inv = 1.0f/ss;
    for (int i=0;i<deg;++i){
      const int e = eids[p0+i];
      const float a = __expf(logits[e]-mx)*inv;
      const float2 u = *reinterpret_cast<const float2*>(uef + (long)e*DIM + lane*2);
      ax += a*u.x; ay += a*u.y;
    }
  }
  unsigned pack = (unsigned)f2b(ax) | ((unsigned)f2b(ay)<<16);
  *reinterpret_cast<unsigned*>(aggb + (long)v*DIM + lane*2) = pack;
}

// ---------- node GRU (one wave per 16-node tile) ----------
__global__ __launch_bounds__(256)
void node_kernel(const u16* __restrict__ aggb, u16* __restrict__ nfb,
                 const float* nf32, float* unf32,            // may alias (in-place iter 2)
                 const u16* __restrict__ Wih, const u16* __restrict__ Whh,
                 const float* __restrict__ bih, const float* __restrict__ bhh)
{
  const int wave = threadIdx.x>>6, lane = threadIdx.x&63;
  const int r16 = lane&15, kq = lane>>4;
  const int tile = blockIdx.x*4 + wave;
  if (tile >= NN/16) return;
  const long v = (long)tile*16 + r16;
  const f32x4 vzero = {0.f,0.f,0.f,0.f};
  bf16x8 xa[4], ha[4];
#pragma unroll
  for (int s=0;s<4;++s){
    xa[s] = ldb8(aggb + v*DIM + s*32 + kq*8);
    ha[s] = ldb8(nfb  + v*DIM + s*32 + kq*8);
  }
#pragma unroll 1
  for (int c=0;c<8;++c){
    f32x4 ar=vzero, az=vzero, an=vzero, hr=vzero, hz=vzero, hn=vzero;
    const u16* wr = Wih + (long)(c*16+r16)*128 + kq*8;
    const u16* vr = Whh + (long)(c*16+r16)*128 + kq*8;
#pragma unroll
    for (int s=0;s<4;++s){
      const int k = s*32;
      ar=MFMA16(xa[s], ldb8(wr+k),         ar,0,0,0);
      az=MFMA16(xa[s], ldb8(wr+k+128*128), az,0,0,0);
      an=MFMA16(xa[s], ldb8(wr+k+256*128), an,0,0,0);
      hr=MFMA16(ha[s], ldb8(vr+k),         hr,0,0,0);
      hz=MFMA16(ha[s], ldb8(vr+k+128*128), hz,0,0,0);
      hn=MFMA16(ha[s], ldb8(vr+k+256*128), hn,0,0,0);
    }
    const int oc = c*16 + r16;
    const float bir=bih[oc], biz=bih[DIM+oc], bin=bih[2*DIM+oc];
    const float bhr=bhh[oc], bhz=bhh[DIM+oc], bhn=bhh[2*DIM+oc];
#pragma unroll
    for (int r=0;r<4;++r){
      const long ee = (long)tile*16 + kq*4 + r;
      float rg = sigm(ar[r]+bir + hr[r]+bhr);
      float zg = sigm(az[r]+biz + hz[r]+bhz);
      float ng = tanh_(an[r]+bin + rg*(hn[r]+bhn));
      float h0 = nf32[ee*DIM+oc];
      float u  = (1.0f-zg)*ng + zg*h0;
      unf32[ee*DIM+oc] = u;
      nfb[ee*DIM+oc] = f2b(u);   // safe: all nfb reads preloaded before chunk loop
    }
  }
}

extern "C" void kernel_launch(void* const* d_in, const int* in_sizes, int n_in,
                              void* d_out, int out_size, void* d_ws, size_t ws_size,
                              hipStream_t stream)
{
  const float* nf_in = (const float*)d_in[0];
  const float* ef_in = (const float*)d_in[1];
  const int*   src   = (const int*)d_in[2];
  const int*   dst   = (const int*)d_in[3];
  const float* eWih  = (const float*)d_in[4];
  const float* eWhh  = (const float*)d_in[5];
  const float* ebih  = (const float*)d_in[6];
  const float* ebhh  = (const float*)d_in[7];
  const float* nWih  = (const float*)d_in[8];
  const float* nWhh  = (const float*)d_in[9];
  const float* nbih  = (const float*)d_in[10];
  const float* nbhh  = (const float*)d_in[11];
  const float* aW1   = (const float*)d_in[12];
  const float* ab1   = (const float*)d_in[13];
  const float* aW2   = (const float*)d_in[14];
  const float* ab2   = (const float*)d_in[15];

  float* nf_out = (float*)d_out;
  float* ef_out = nf_out + (size_t)NN*DIM;

  // workspace carve (~133 MB needed)
  char* p = (char*)d_ws;
  auto carve = [&](size_t bytes)->void*{ void* r = (void*)p; p += (bytes + 255) & ~(size_t)255; return r; };
  u16* efb    = (u16*)carve((size_t)NE*DIM*2);
  u16* nfb    = (u16*)carve((size_t)NN*DIM*2);
  u16* aggb   = (u16*)carve((size_t)NN*DIM*2);
  float* logits = (float*)carve((size_t)NE*4);
  int* eids   = (int*)carve((size_t)NE*4);
  int* counts = (int*)carve((size_t)NN*4);
  int* rowp   = (int*)carve((size_t)(NN+1)*4);
  int* cursor = (int*)carve((size_t)NN*4);
  u16* bWih   = (u16*)carve((size_t)384*256*2);
  u16* bWhh   = (u16*)carve((size_t)384*128*2);
  u16* bnWih  = (u16*)carve((size_t)384*128*2);
  u16* bnWhh  = (u16*)carve((size_t)384*128*2);
  u16* baW1T  = (u16*)carve((size_t)128*128*2);

  // bf16 conversions (once per launch)
  f2b_kernel<<<2048,256,0,stream>>>(nf_in, nfb, NN*DIM/4);
  f2b_kernel<<<2048,256,0,stream>>>(ef_in, efb, NE*DIM/4);
  f2b_kernel<<<96,256,0,stream>>>(eWih, bWih, 384*256/4);
  f2b_kernel<<<48,256,0,stream>>>(eWhh, bWhh, 384*128/4);
  f2b_kernel<<<48,256,0,stream>>>(nWih, bnWih, 384*128/4);
  f2b_kernel<<<48,256,0,stream>>>(nWhh, bnWhh, 384*128/4);
  transpose128_kernel<<<64,256,0,stream>>>(aW1, baW1T);

  // CSR over dst (dst is constant across iterations)
  zero_kernel<<<(NN+255)/256,256,0,stream>>>(counts, NN);
  hist_kernel<<<(NE+255)/256,256,0,stream>>>(dst, counts, NE);
  scan_kernel<<<1,1024,0,stream>>>(counts, rowp, cursor, NN);
  scatter_kernel<<<(NE+255)/256,256,0,stream>>>(dst, cursor, eids, NE);

  for (int it=0; it<2; ++it){
    const float* ef_cur = (it==0) ? ef_in : ef_out;
    const float* nf_cur = (it==0) ? nf_in : nf_out;
    edge_kernel<<<NE/64,256,0,stream>>>(src, dst, nfb, efb, ef_cur, ef_out,
                                        bWih, bWhh, ebih, ebhh,
                                        baW1T, ab1, aW2, ab2, logits);
    agg_kernel<<<(NN+3)/4,256,0,stream>>>(rowp, eids, logits, ef_out, aggb);
    node_kernel<<<(NN/16+3)/4,256,0,stream>>>(aggb, nfb, nf_cur, nf_out,
                                              bnWih, bnWhh, nbih, nbhh);
  }
}

// Round 2
// 2341.763 us; speedup vs baseline: 1.0572x; 1.0572x over previous
//
#include <hip/hip_runtime.h>

#define NN 50000
#define NE 400000
#define DIM 128

typedef __bf16 bf16x8 __attribute__((ext_vector_type(8)));
typedef float f32x4 __attribute__((ext_vector_type(4)));
typedef unsigned short u16;

#define MFMA16 __builtin_amdgcn_mfma_f32_16x16x32_bf16

__device__ __forceinline__ u16 f2b(float f){ __bf16 b=(__bf16)f; return __builtin_bit_cast(u16,b); }
__device__ __forceinline__ float b2f(u16 h){ unsigned u = ((unsigned)h)<<16; return __builtin_bit_cast(float,u); }
__device__ __forceinline__ float sigm(float x){ return 1.0f/(1.0f+__expf(-x)); }
__device__ __forceinline__ float tanh_(float x){ float e=__expf(2.0f*x); return 1.0f-2.0f/(e+1.0f); }
__device__ __forceinline__ bf16x8 ldb8(const u16* p){ return *reinterpret_cast<const bf16x8*>(p); }

// ---------- utility kernels ----------
__global__ void f2b_kernel(const float* __restrict__ in, u16* __restrict__ out, int n4){
  int i = blockIdx.x*blockDim.x + threadIdx.x;
  int st = gridDim.x*blockDim.x;
  for (; i<n4; i+=st){
    float4 v = reinterpret_cast<const float4*>(in)[i];
    ushort4 o = { f2b(v.x), f2b(v.y), f2b(v.z), f2b(v.w) };
    reinterpret_cast<ushort4*>(out)[i] = o;
  }
}

__global__ void transpose128_kernel(const float* __restrict__ in, u16* __restrict__ out){
  int i = blockIdx.x*blockDim.x + threadIdx.x; // 16384 threads total
  int k = i>>7, n = i&127;
  out[n*128+k] = f2b(in[i]);   // out[n][k] = in[k][n]
}

__global__ void zero_kernel(int* p, int n){
  int i = blockIdx.x*blockDim.x + threadIdx.x; if (i<n) p[i]=0;
}
__global__ void hist_kernel(const int* __restrict__ dst, int* __restrict__ counts, int n){
  int i = blockIdx.x*blockDim.x + threadIdx.x; if (i<n) atomicAdd(&counts[dst[i]],1);
}
__global__ void scan_kernel(const int* __restrict__ counts, int* __restrict__ rowp,
                            int* __restrict__ cursor, int n){
  __shared__ int buf[1024];
  __shared__ int run;
  const int t = threadIdx.x;
  if (t==0) run = 0;
  __syncthreads();
  for (int base=0; base<n; base+=1024){
    int v = (base+t<n) ? counts[base+t] : 0;
    buf[t]=v; __syncthreads();
    for (int off=1; off<1024; off<<=1){
      int x = (t>=off) ? buf[t-off] : 0;
      __syncthreads();
      buf[t]+=x; __syncthreads();
    }
    int incl = buf[t];
    int br = run;
    __syncthreads();
    if (base+t<n){ int ex = br+incl-v; rowp[base+t]=ex; cursor[base+t]=ex; }
    if (t==1023) run = br+incl;
    __syncthreads();
  }
  if (t==0) rowp[n]=run;
}
__global__ void scatter_kernel(const int* __restrict__ dst, int* __restrict__ cursor,
                               int* __restrict__ eids, int n){
  int i = blockIdx.x*blockDim.x + threadIdx.x;
  if (i<n){ int p = atomicAdd(&cursor[dst[i]],1); eids[p]=i; }
}

// ---------- edge GRU + attention MLP (v2: M-split, barrier-free, bf16 state) ----------
// WG = 256 = 4 independent waves; each wave owns 16 DISTINCT edges (A-frags loaded
// once into regs), loops over 8 output chunks with weight B-frags from L2.
// MFMA frag: A lane holds A[row=l&15][k=8*(l>>4)+j]; B lane holds W[col=l&15][same k];
// C/D: col=l&15, row=(l>>4)*4+reg  [verified learn_hip m89].
__global__ __launch_bounds__(256)
void edge_kernel(const int* __restrict__ src, const int* __restrict__ dst,
                 const u16* __restrict__ nfb, u16* __restrict__ efb,
                 const u16* __restrict__ Wih, const u16* __restrict__ Whh,
                 const float* __restrict__ bih, const float* __restrict__ bhh,
                 const u16* __restrict__ aW1T, const float* __restrict__ ab1,
                 const float* __restrict__ aW2, const float* __restrict__ ab2,
                 float* __restrict__ logits, float* __restrict__ ef32out)
{
  __shared__ __align__(16) u16 u_lds[4*16*DIM];   // 16 KB, 4 KB per wave, XOR-swizzled rows
  const int wave = threadIdx.x>>6, lane = threadIdx.x&63;
  const int r16 = lane&15, kq = lane>>4;
  const long base = (long)blockIdx.x*64 + wave*16;
  const long e = base + r16;
  const u16* sp = nfb + (long)src[e]*DIM;
  const u16* dp = nfb + (long)dst[e]*DIM;
  const u16* ep = efb + e*DIM;
  u16* tile = u_lds + wave*16*DIM;

  // A-fragments, loaded ONCE: gi K=256 (src|dst halves), gh K=128 (ef)
  bf16x8 ag[8], ae[4];
#pragma unroll
  for (int s=0;s<4;++s){
    ag[s]   = ldb8(sp + s*32 + kq*8);
    ag[s+4] = ldb8(dp + s*32 + kq*8);
    ae[s]   = ldb8(ep + s*32 + kq*8);
  }
  const f32x4 vzero = {0.f,0.f,0.f,0.f};

#pragma unroll 1
  for (int c=0;c<8;++c){
    const int oc = c*16 + r16;
    const u16* w = Wih + (long)oc*256 + kq*8;
    const u16* v = Whh + (long)oc*128 + kq*8;
    f32x4 ar=vzero, az=vzero, an=vzero, hr=vzero, hz=vzero, hn=vzero;
#pragma unroll
    for (int s=0;s<8;++s){
      ar = MFMA16(ag[s], ldb8(w + s*32),           ar,0,0,0);
      az = MFMA16(ag[s], ldb8(w + s*32 + 128*256), az,0,0,0);
      an = MFMA16(ag[s], ldb8(w + s*32 + 256*256), an,0,0,0);
    }
#pragma unroll
    for (int s=0;s<4;++s){
      hr = MFMA16(ae[s], ldb8(v + s*32),           hr,0,0,0);
      hz = MFMA16(ae[s], ldb8(v + s*32 + 128*128), hz,0,0,0);
      hn = MFMA16(ae[s], ldb8(v + s*32 + 256*128), hn,0,0,0);
    }
    const float bir=bih[oc], biz=bih[DIM+oc], bin=bih[2*DIM+oc];
    const float bhr=bhh[oc], bhz=bhh[DIM+oc], bhn=bhh[2*DIM+oc];
#pragma unroll
    for (int r=0;r<4;++r){
      const int row = kq*4+r;
      const long er = base + row;
      float rg = sigm(ar[r]+bir + hr[r]+bhr);
      float zg = sigm(az[r]+biz + hz[r]+bhz);
      float ng = tanh_(an[r]+bin + rg*(hn[r]+bhn));
      float h0 = b2f(efb[er*DIM+oc]);            // L1-hot (this wave's ef rows)
      float u  = (1.0f-zg)*ng + zg*h0;
      *(u16*)((char*)tile + row*256 + ((c*32 + r16*2) ^ ((row&7)<<4))) = f2b(u);
      if (ef32out) ef32out[er*DIM+oc] = u;       // last iteration: fp32 output
    }
  }

  // attention MLP on this wave's 16 uef rows (LDS, same-wave, no barrier)
  bf16x8 ua[4];
#pragma unroll
  for (int s=0;s<4;++s)
    ua[s] = ldb8((const u16*)((const char*)tile + r16*256 + ((s*64 + kq*16) ^ ((r16&7)<<4))));
  float part[4] = {0.f,0.f,0.f,0.f};
#pragma unroll 1
  for (int t=0;t<8;++t){
    f32x4 h = vzero;
#pragma unroll
    for (int s=0;s<4;++s)
      h = MFMA16(ua[s], ldb8(aW1T + (long)(t*16+r16)*128 + s*32 + kq*8), h,0,0,0);
    const int cc = t*16 + r16;
    const float b1 = ab1[cc], w2 = aW2[cc];
#pragma unroll
    for (int r=0;r<4;++r) part[r] += fmaxf(h[r]+b1, 0.f)*w2;
  }
#pragma unroll
  for (int off=1; off<16; off<<=1){
#pragma unroll
    for (int r=0;r<4;++r) part[r] += __shfl_xor(part[r], off, 64);
  }
  if (r16==0){
    const float b2v = ab2[0];
#pragma unroll
    for (int r=0;r<4;++r) logits[base + kq*4 + r] = part[r] + b2v;
  }

  // vectorized LDS -> efb copy (in-place bf16 state update; all efb reads done)
#pragma unroll
  for (int i2=0;i2<4;++i2){
    const int idx = i2*64 + lane;
    const int row = idx>>4, slot = idx&15;
    uint4 val = *(const uint4*)((const char*)tile + row*256 + ((slot*16) ^ ((row&7)<<4)));
    *(uint4*)(efb + (base+row)*DIM + slot*8) = val;
  }
}

// ---------- softmax + weighted aggregation (CSR, one wave per node, bf16 uef) ----------
__global__ __launch_bounds__(256)
void agg_kernel(const int* __restrict__ rowp, const int* __restrict__ eids,
                const float* __restrict__ logits, const u16* __restrict__ uefb,
                u16* __restrict__ aggb)
{
  const int wave = threadIdx.x>>6, lane = threadIdx.x&63;
  const int v = blockIdx.x*4 + wave;
  if (v>=NN) return;
  const int p0 = rowp[v], deg = rowp[v+1]-p0;
  float ax=0.f, ay=0.f;
  if (deg>0){
    float mx = -__builtin_inff();
    for (int i=lane; i<deg; i+=64) mx = fmaxf(mx, logits[eids[p0+i]]);
#pragma unroll
    for (int off=32; off; off>>=1) mx = fmaxf(mx, __shfl_xor(mx, off, 64));
    float ss = 0.f;
    for (int i=lane; i<deg; i+=64) ss += __expf(logits[eids[p0+i]] - mx);
#pragma unroll
    for (int off=32; off; off>>=1) ss += __shfl_xor(ss, off, 64);
    const float inv = 1.0f/ss;
    int i = 0;
    for (; i+2<=deg; i+=2){
      const int e0 = eids[p0+i], e1 = eids[p0+i+1];
      const float l0 = logits[e0], l1 = logits[e1];
      const unsigned q0 = *reinterpret_cast<const unsigned*>(uefb + (long)e0*DIM + lane*2);
      const unsigned q1 = *reinterpret_cast<const unsigned*>(uefb + (long)e1*DIM + lane*2);
      const float a0 = __expf(l0-mx)*inv, a1 = __expf(l1-mx)*inv;
      ax += a0*b2f((u16)q0) + a1*b2f((u16)q1);
      ay += a0*b2f((u16)(q0>>16)) + a1*b2f((u16)(q1>>16));
    }
    if (i<deg){
      const int e0 = eids[p0+i];
      const float a0 = __expf(logits[e0]-mx)*inv;
      const unsigned q0 = *reinterpret_cast<const unsigned*>(uefb + (long)e0*DIM + lane*2);
      ax += a0*b2f((u16)q0);
      ay += a0*b2f((u16)(q0>>16));
    }
  }
  unsigned pack = (unsigned)f2b(ax) | ((unsigned)f2b(ay)<<16);
  *reinterpret_cast<unsigned*>(aggb + (long)v*DIM + lane*2) = pack;
}

// ---------- node GRU (one wave per 16-node tile) ----------
__global__ __launch_bounds__(256)
void node_kernel(const u16* __restrict__ aggb, u16* __restrict__ nfb,
                 const float* nf32, float* unf32,            // may alias (in-place iter 2)
                 const u16* __restrict__ Wih, const u16* __restrict__ Whh,
                 const float* __restrict__ bih, const float* __restrict__ bhh)
{
  const int wave = threadIdx.x>>6, lane = threadIdx.x&63;
  const int r16 = lane&15, kq = lane>>4;
  const int tile = blockIdx.x*4 + wave;
  if (tile >= NN/16) return;
  const long v = (long)tile*16 + r16;
  const f32x4 vzero = {0.f,0.f,0.f,0.f};
  bf16x8 xa[4], ha[4];
#pragma unroll
  for (int s=0;s<4;++s){
    xa[s] = ldb8(aggb + v*DIM + s*32 + kq*8);
    ha[s] = ldb8(nfb  + v*DIM + s*32 + kq*8);
  }
#pragma unroll 1
  for (int c=0;c<8;++c){
    f32x4 ar=vzero, az=vzero, an=vzero, hr=vzero, hz=vzero, hn=vzero;
    const u16* wr = Wih + (long)(c*16+r16)*128 + kq*8;
    const u16* vr = Whh + (long)(c*16+r16)*128 + kq*8;
#pragma unroll
    for (int s=0;s<4;++s){
      const int k = s*32;
      ar=MFMA16(xa[s], ldb8(wr+k),         ar,0,0,0);
      az=MFMA16(xa[s], ldb8(wr+k+128*128), az,0,0,0);
      an=MFMA16(xa[s], ldb8(wr+k+256*128), an,0,0,0);
      hr=MFMA16(ha[s], ldb8(vr+k),         hr,0,0,0);
      hz=MFMA16(ha[s], ldb8(vr+k+128*128), hz,0,0,0);
      hn=MFMA16(ha[s], ldb8(vr+k+256*128), hn,0,0,0);
    }
    const int oc = c*16 + r16;
    const float bir=bih[oc], biz=bih[DIM+oc], bin=bih[2*DIM+oc];
    const float bhr=bhh[oc], bhz=bhh[DIM+oc], bhn=bhh[2*DIM+oc];
#pragma unroll
    for (int r=0;r<4;++r){
      const long ee = (long)tile*16 + kq*4 + r;
      float rg = sigm(ar[r]+bir + hr[r]+bhr);
      float zg = sigm(az[r]+biz + hz[r]+bhz);
      float ng = tanh_(an[r]+bin + rg*(hn[r]+bhn));
      float h0 = nf32[ee*DIM+oc];
      float u  = (1.0f-zg)*ng + zg*h0;
      unf32[ee*DIM+oc] = u;
      nfb[ee*DIM+oc] = f2b(u);   // safe: all nfb reads preloaded before chunk loop
    }
  }
}

extern "C" void kernel_launch(void* const* d_in, const int* in_sizes, int n_in,
                              void* d_out, int out_size, void* d_ws, size_t ws_size,
                              hipStream_t stream)
{
  const float* nf_in = (const float*)d_in[0];
  const float* ef_in = (const float*)d_in[1];
  const int*   src   = (const int*)d_in[2];
  const int*   dst   = (const int*)d_in[3];
  const float* eWih  = (const float*)d_in[4];
  const float* eWhh  = (const float*)d_in[5];
  const float* ebih  = (const float*)d_in[6];
  const float* ebhh  = (const float*)d_in[7];
  const float* nWih  = (const float*)d_in[8];
  const float* nWhh  = (const float*)d_in[9];
  const float* nbih  = (const float*)d_in[10];
  const float* nbhh  = (const float*)d_in[11];
  const float* aW1   = (const float*)d_in[12];
  const float* ab1   = (const float*)d_in[13];
  const float* aW2   = (const float*)d_in[14];
  const float* ab2   = (const float*)d_in[15];

  float* nf_out = (float*)d_out;
  float* ef_out = nf_out + (size_t)NN*DIM;

  // workspace carve
  char* p = (char*)d_ws;
  auto carve = [&](size_t bytes)->void*{ void* r = (void*)p; p += (bytes + 255) & ~(size_t)255; return r; };
  u16* efb    = (u16*)carve((size_t)NE*DIM*2);
  u16* nfb    = (u16*)carve((size_t)NN*DIM*2);
  u16* aggb   = (u16*)carve((size_t)NN*DIM*2);
  float* logits = (float*)carve((size_t)NE*4);
  int* eids   = (int*)carve((size_t)NE*4);
  int* counts = (int*)carve((size_t)NN*4);
  int* rowp   = (int*)carve((size_t)(NN+1)*4);
  int* cursor = (int*)carve((size_t)NN*4);
  u16* bWih   = (u16*)carve((size_t)384*256*2);
  u16* bWhh   = (u16*)carve((size_t)384*128*2);
  u16* bnWih  = (u16*)carve((size_t)384*128*2);
  u16* bnWhh  = (u16*)carve((size_t)384*128*2);
  u16* baW1T  = (u16*)carve((size_t)128*128*2);

  // bf16 conversions (once per launch)
  f2b_kernel<<<2048,256,0,stream>>>(nf_in, nfb, NN*DIM/4);
  f2b_kernel<<<2048,256,0,stream>>>(ef_in, efb, NE*DIM/4);
  f2b_kernel<<<96,256,0,stream>>>(eWih, bWih, 384*256/4);
  f2b_kernel<<<48,256,0,stream>>>(eWhh, bWhh, 384*128/4);
  f2b_kernel<<<48,256,0,stream>>>(nWih, bnWih, 384*128/4);
  f2b_kernel<<<48,256,0,stream>>>(nWhh, bnWhh, 384*128/4);
  transpose128_kernel<<<64,256,0,stream>>>(aW1, baW1T);

  // CSR over dst (constant across iterations)
  zero_kernel<<<(NN+255)/256,256,0,stream>>>(counts, NN);
  hist_kernel<<<(NE+255)/256,256,0,stream>>>(dst, counts, NE);
  scan_kernel<<<1,1024,0,stream>>>(counts, rowp, cursor, NN);
  scatter_kernel<<<(NE+255)/256,256,0,stream>>>(dst, cursor, eids, NE);

  for (int it=0; it<2; ++it){
    const float* nf_cur = (it==0) ? nf_in : nf_out;
    float* efout32 = (it==1) ? ef_out : nullptr;
    edge_kernel<<<NE/64,256,0,stream>>>(src, dst, nfb, efb,
                                        bWih, bWhh, ebih, ebhh,
                                        baW1T, ab1, aW2, ab2, logits, efout32);
    agg_kernel<<<(NN+3)/4,256,0,stream>>>(rowp, eids, logits, efb, aggb);
    node_kernel<<<(NN/16+3)/4,256,0,stream>>>(aggb, nfb, nf_cur, nf_out,
                                              bnWih, bnWhh, nbih, nbhh);
  }
}

// Round 3
// 1880.375 us; speedup vs baseline: 1.3166x; 1.2454x over previous
//
#include <hip/hip_runtime.h>

#define NN 50000
#define NE 400000
#define DIM 128

typedef __bf16 bf16x8 __attribute__((ext_vector_type(8)));
typedef float f32x4 __attribute__((ext_vector_type(4)));
typedef unsigned short u16;

#define MFMA16 __builtin_amdgcn_mfma_f32_16x16x32_bf16

__device__ __forceinline__ u16 f2b(float f){ __bf16 b=(__bf16)f; return __builtin_bit_cast(u16,b); }
__device__ __forceinline__ float b2f(u16 h){ unsigned u = ((unsigned)h)<<16; return __builtin_bit_cast(float,u); }
__device__ __forceinline__ float sigm(float x){ return 1.0f/(1.0f+__expf(-x)); }
__device__ __forceinline__ float tanh_(float x){ float e=__expf(2.0f*x); return 1.0f-2.0f/(e+1.0f); }
__device__ __forceinline__ bf16x8 ldb8(const u16* p){ return *reinterpret_cast<const bf16x8*>(p); }

#define GLOAD_LDS(gp, lp) __builtin_amdgcn_global_load_lds( \
    (const __attribute__((address_space(1))) void*)(gp),    \
    (__attribute__((address_space(3))) void*)(lp), 16, 0, 0)

// ---------- utility kernels ----------
__global__ void f2b_kernel(const float* __restrict__ in, u16* __restrict__ out, int n4){
  int i = blockIdx.x*blockDim.x + threadIdx.x;
  int st = gridDim.x*blockDim.x;
  for (; i<n4; i+=st){
    float4 v = reinterpret_cast<const float4*>(in)[i];
    ushort4 o = { f2b(v.x), f2b(v.y), f2b(v.z), f2b(v.w) };
    reinterpret_cast<ushort4*>(out)[i] = o;
  }
}

__global__ void transpose128_kernel(const float* __restrict__ in, u16* __restrict__ out){
  int i = blockIdx.x*blockDim.x + threadIdx.x; // 16384 threads total
  int k = i>>7, n = i&127;
  out[n*128+k] = f2b(in[i]);   // out[n][k] = in[k][n]
}

__global__ void zero_kernel(int* p, int n){
  int i = blockIdx.x*blockDim.x + threadIdx.x; if (i<n) p[i]=0;
}
__global__ void hist_kernel(const int* __restrict__ dst, int* __restrict__ counts, int n){
  int i = blockIdx.x*blockDim.x + threadIdx.x; if (i<n) atomicAdd(&counts[dst[i]],1);
}
__global__ void scan_kernel(const int* __restrict__ counts, int* __restrict__ rowp,
                            int* __restrict__ cursor, int n){
  __shared__ int buf[1024];
  __shared__ int run;
  const int t = threadIdx.x;
  if (t==0) run = 0;
  __syncthreads();
  for (int base=0; base<n; base+=1024){
    int v = (base+t<n) ? counts[base+t] : 0;
    buf[t]=v; __syncthreads();
    for (int off=1; off<1024; off<<=1){
      int x = (t>=off) ? buf[t-off] : 0;
      __syncthreads();
      buf[t]+=x; __syncthreads();
    }
    int incl = buf[t];
    int br = run;
    __syncthreads();
    if (base+t<n){ int ex = br+incl-v; rowp[base+t]=ex; cursor[base+t]=ex; }
    if (t==1023) run = br+incl;
    __syncthreads();
  }
  if (t==0) rowp[n]=run;
}
__global__ void scatter_kernel(const int* __restrict__ dst, int* __restrict__ cursor,
                               int* __restrict__ eids, int n){
  int i = blockIdx.x*blockDim.x + threadIdx.x;
  if (i<n){ int p = atomicAdd(&cursor[dst[i]],1); eids[p]=i; }
}

// ---------- edge GRU + attention MLP (v3: LDS-staged weights) ----------
// 512 threads = 8 waves x 16 edges = 128 edges/block. Per output chunk c (16 cols),
// the 36KB weight slice (3 gates x [Wih 16x256 + Whh 16x128]) is staged into ONE
// LDS buffer via global_load_lds in FRAGMENT-MAJOR layout: frag f at buf+f*1024,
// lane i at +i*16 (linear gload_lds write == MFMA B-frag read, conflict-free).
// Single buffer -> 36KB LDS -> 4 blocks/CU; 2 barriers/chunk; stage(c+1) issued
// after the consume-barrier, latency covered by gate epilogue + other blocks.
// Attn MLP = 9th staged chunk (aW1T). uef stored to global per chunk (bf16),
// re-read L1-hot for the attn A-frags. In-place efb safe: (row,col) read in
// chunk c=col/16 before its store; h0 read at chunk start, stored at chunk end.
__global__ __launch_bounds__(512, 8)
void edge_kernel(const int* __restrict__ src, const int* __restrict__ dst,
                 const u16* __restrict__ nfb, u16* __restrict__ efb,
                 const u16* __restrict__ Wih, const u16* __restrict__ Whh,
                 const float* __restrict__ bih, const float* __restrict__ bhh,
                 const u16* __restrict__ aW1T, const float* __restrict__ ab1,
                 const float* __restrict__ aW2, const float* __restrict__ ab2,
                 float* __restrict__ logits, float* __restrict__ ef32out)
{
  __shared__ __align__(16) u16 wbuf[36*512];   // 36 KB, frag-major
  const int wave = threadIdx.x>>6, lane = threadIdx.x&63;
  const int r16 = lane&15, kq = lane>>4;
  const long base = (long)blockIdx.x*128 + wave*16;
  const long e = base + r16;

  // cooperative staging of chunk c's weight frags (c=8 -> attention weights)
  auto stage = [&](int c){
    if (c < 8){
      for (int f = wave; f < 36; f += 8){
        const u16* g;
        if (f < 24){ const int gt = f>>3, s = f&7;
          g = Wih + (long)(gt*128 + c*16 + r16)*256 + s*32 + kq*8; }
        else { const int q = f-24, gt = q>>2, s = q&3;
          g = Whh + (long)(gt*128 + c*16 + r16)*128 + s*32 + kq*8; }
        GLOAD_LDS(g, wbuf + f*512);
      }
    } else {
      for (int f = wave; f < 32; f += 8){
        const int t = f>>2, s = f&3;
        GLOAD_LDS(aW1T + (long)(t*16 + r16)*128 + s*32 + kq*8, wbuf + f*512);
      }
    }
  };

  // A-fragments, loaded once: gi K=256 (src|dst), gh K=128 (ef)
  const u16* sp = nfb + (long)src[e]*DIM;
  const u16* dp = nfb + (long)dst[e]*DIM;
  const u16* ep = efb + e*DIM;
  bf16x8 ag[8], ae[4];
#pragma unroll
  for (int s=0;s<4;++s){
    ag[s]   = ldb8(sp + s*32 + kq*8);
    ag[s+4] = ldb8(dp + s*32 + kq*8);
    ae[s]   = ldb8(ep + s*32 + kq*8);
  }
  stage(0);
  __syncthreads();

  const f32x4 vzero = {0.f,0.f,0.f,0.f};
  const u16* lbase = wbuf + lane*8;   // frag f => lbase + f*512 (u16 units)

#pragma unroll 1
  for (int c=0;c<8;++c){
    const int oc = c*16 + r16;
    // early vmem: biases + this chunk's h0 (latency covered by MFMA phase)
    const float bir=bih[oc], biz=bih[DIM+oc], bin=bih[2*DIM+oc];
    const float bhr=bhh[oc], bhz=bhh[DIM+oc], bhn=bhh[2*DIM+oc];
    float h0p[4];
#pragma unroll
    for (int r=0;r<4;++r) h0p[r] = b2f(efb[(base+kq*4+r)*DIM + oc]);

    f32x4 ar=vzero, az=vzero, an=vzero, hr=vzero, hz=vzero, hn=vzero;
#pragma unroll
    for (int s=0;s<8;++s){
      ar = MFMA16(ag[s], ldb8(lbase + ( s   )*512), ar,0,0,0);
      az = MFMA16(ag[s], ldb8(lbase + ( 8+s )*512), az,0,0,0);
      an = MFMA16(ag[s], ldb8(lbase + (16+s )*512), an,0,0,0);
    }
#pragma unroll
    for (int s=0;s<4;++s){
      hr = MFMA16(ae[s], ldb8(lbase + (24+s)*512), hr,0,0,0);
      hz = MFMA16(ae[s], ldb8(lbase + (28+s)*512), hz,0,0,0);
      hn = MFMA16(ae[s], ldb8(lbase + (32+s)*512), hn,0,0,0);
    }
    __syncthreads();              // all waves done reading wbuf
    stage(c+1);                   // fire-and-forget refill (c+1 <= 8)
    // gate epilogue (register-only + stores) overlaps the stage latency
#pragma unroll
    for (int r=0;r<4;++r){
      const long er = base + kq*4 + r;
      float rg = sigm(ar[r]+bir + hr[r]+bhr);
      float zg = sigm(az[r]+biz + hz[r]+bhz);
      float ng = tanh_(an[r]+bin + rg*(hn[r]+bhn));
      float u  = (1.0f-zg)*ng + zg*h0p[r];
      efb[er*DIM+oc] = f2b(u);
      if (ef32out) ef32out[er*DIM+oc] = u;
    }
    __syncthreads();              // wbuf refilled; stores drained
  }

  // ----- attention MLP: chunk 8 (aW1T) is in wbuf; uef rows re-read L1-hot -----
  bf16x8 ua[4];
#pragma unroll
  for (int s=0;s<4;++s) ua[s] = ldb8(ep + s*32 + kq*8);   // ep = efb row e (now uef)
  float part[4] = {0.f,0.f,0.f,0.f};
#pragma unroll 1
  for (int t=0;t<8;++t){
    f32x4 h = vzero;
#pragma unroll
    for (int s=0;s<4;++s)
      h = MFMA16(ua[s], ldb8(lbase + (t*4+s)*512), h,0,0,0);
    const int cc = t*16 + r16;
    const float b1 = ab1[cc], w2 = aW2[cc];
#pragma unroll
    for (int r=0;r<4;++r) part[r] += fmaxf(h[r]+b1, 0.f)*w2;
  }
#pragma unroll
  for (int off=1; off<16; off<<=1){
#pragma unroll
    for (int r=0;r<4;++r) part[r] += __shfl_xor(part[r], off, 64);
  }
  if (r16==0){
    const float b2v = ab2[0];
#pragma unroll
    for (int r=0;r<4;++r) logits[base + kq*4 + r] = part[r] + b2v;
  }
}

// ---------- softmax + weighted aggregation (CSR, one wave per node, bf16 uef) ----------
__global__ __launch_bounds__(256)
void agg_kernel(const int* __restrict__ rowp, const int* __restrict__ eids,
                const float* __restrict__ logits, const u16* __restrict__ uefb,
                u16* __restrict__ aggb)
{
  const int wave = threadIdx.x>>6, lane = threadIdx.x&63;
  const int v = blockIdx.x*4 + wave;
  if (v>=NN) return;
  const int p0 = rowp[v], deg = rowp[v+1]-p0;
  float ax=0.f, ay=0.f;
  if (deg>0){
    float mx = -__builtin_inff();
    for (int i=lane; i<deg; i+=64) mx = fmaxf(mx, logits[eids[p0+i]]);
#pragma unroll
    for (int off=32; off; off>>=1) mx = fmaxf(mx, __shfl_xor(mx, off, 64));
    float ss = 0.f;
    for (int i=lane; i<deg; i+=64) ss += __expf(logits[eids[p0+i]] - mx);
#pragma unroll
    for (int off=32; off; off>>=1) ss += __shfl_xor(ss, off, 64);
    const float inv = 1.0f/ss;
    int i = 0;
    for (; i+2<=deg; i+=2){
      const int e0 = eids[p0+i], e1 = eids[p0+i+1];
      const float l0 = logits[e0], l1 = logits[e1];
      const unsigned q0 = *reinterpret_cast<const unsigned*>(uefb + (long)e0*DIM + lane*2);
      const unsigned q1 = *reinterpret_cast<const unsigned*>(uefb + (long)e1*DIM + lane*2);
      const float a0 = __expf(l0-mx)*inv, a1 = __expf(l1-mx)*inv;
      ax += a0*b2f((u16)q0) + a1*b2f((u16)q1);
      ay += a0*b2f((u16)(q0>>16)) + a1*b2f((u16)(q1>>16));
    }
    if (i<deg){
      const int e0 = eids[p0+i];
      const float a0 = __expf(logits[e0]-mx)*inv;
      const unsigned q0 = *reinterpret_cast<const unsigned*>(uefb + (long)e0*DIM + lane*2);
      ax += a0*b2f((u16)q0);
      ay += a0*b2f((u16)(q0>>16));
    }
  }
  unsigned pack = (unsigned)f2b(ax) | ((unsigned)f2b(ay)<<16);
  *reinterpret_cast<unsigned*>(aggb + (long)v*DIM + lane*2) = pack;
}

// ---------- node GRU (one wave per 16-node tile) ----------
__global__ __launch_bounds__(256)
void node_kernel(const u16* __restrict__ aggb, u16* __restrict__ nfb,
                 const float* nf32, float* unf32,            // may alias (in-place iter 2)
                 const u16* __restrict__ Wih, const u16* __restrict__ Whh,
                 const float* __restrict__ bih, const float* __restrict__ bhh)
{
  const int wave = threadIdx.x>>6, lane = threadIdx.x&63;
  const int r16 = lane&15, kq = lane>>4;
  const int tile = blockIdx.x*4 + wave;
  if (tile >= NN/16) return;
  const long v = (long)tile*16 + r16;
  const f32x4 vzero = {0.f,0.f,0.f,0.f};
  bf16x8 xa[4], ha[4];
#pragma unroll
  for (int s=0;s<4;++s){
    xa[s] = ldb8(aggb + v*DIM + s*32 + kq*8);
    ha[s] = ldb8(nfb  + v*DIM + s*32 + kq*8);
  }
#pragma unroll 1
  for (int c=0;c<8;++c){
    f32x4 ar=vzero, az=vzero, an=vzero, hr=vzero, hz=vzero, hn=vzero;
    const u16* wr = Wih + (long)(c*16+r16)*128 + kq*8;
    const u16* vr = Whh + (long)(c*16+r16)*128 + kq*8;
#pragma unroll
    for (int s=0;s<4;++s){
      const int k = s*32;
      ar=MFMA16(xa[s], ldb8(wr+k),         ar,0,0,0);
      az=MFMA16(xa[s], ldb8(wr+k+128*128), az,0,0,0);
      an=MFMA16(xa[s], ldb8(wr+k+256*128), an,0,0,0);
      hr=MFMA16(ha[s], ldb8(vr+k),         hr,0,0,0);
      hz=MFMA16(ha[s], ldb8(vr+k+128*128), hz,0,0,0);
      hn=MFMA16(ha[s], ldb8(vr+k+256*128), hn,0,0,0);
    }
    const int oc = c*16 + r16;
    const float bir=bih[oc], biz=bih[DIM+oc], bin=bih[2*DIM+oc];
    const float bhr=bhh[oc], bhz=bhh[DIM+oc], bhn=bhh[2*DIM+oc];
#pragma unroll
    for (int r=0;r<4;++r){
      const long ee = (long)tile*16 + kq*4 + r;
      float rg = sigm(ar[r]+bir + hr[r]+bhr);
      float zg = sigm(az[r]+biz + hz[r]+bhz);
      float ng = tanh_(an[r]+bin + rg*(hn[r]+bhn));
      float h0 = nf32[ee*DIM+oc];
      float u  = (1.0f-zg)*ng + zg*h0;
      unf32[ee*DIM+oc] = u;
      nfb[ee*DIM+oc] = f2b(u);   // safe: all nfb reads preloaded before chunk loop
    }
  }
}

extern "C" void kernel_launch(void* const* d_in, const int* in_sizes, int n_in,
                              void* d_out, int out_size, void* d_ws, size_t ws_size,
                              hipStream_t stream)
{
  const float* nf_in = (const float*)d_in[0];
  const float* ef_in = (const float*)d_in[1];
  const int*   src   = (const int*)d_in[2];
  const int*   dst   = (const int*)d_in[3];
  const float* eWih  = (const float*)d_in[4];
  const float* eWhh  = (const float*)d_in[5];
  const float* ebih  = (const float*)d_in[6];
  const float* ebhh  = (const float*)d_in[7];
  const float* nWih  = (const float*)d_in[8];
  const float* nWhh  = (const float*)d_in[9];
  const float* nbih  = (const float*)d_in[10];
  const float* nbhh  = (const float*)d_in[11];
  const float* aW1   = (const float*)d_in[12];
  const float* ab1   = (const float*)d_in[13];
  const float* aW2   = (const float*)d_in[14];
  const float* ab2   = (const float*)d_in[15];

  float* nf_out = (float*)d_out;
  float* ef_out = nf_out + (size_t)NN*DIM;

  // workspace carve
  char* p = (char*)d_ws;
  auto carve = [&](size_t bytes)->void*{ void* r = (void*)p; p += (bytes + 255) & ~(size_t)255; return r; };
  u16* efb    = (u16*)carve((size_t)NE*DIM*2);
  u16* nfb    = (u16*)carve((size_t)NN*DIM*2);
  u16* aggb   = (u16*)carve((size_t)NN*DIM*2);
  float* logits = (float*)carve((size_t)NE*4);
  int* eids   = (int*)carve((size_t)NE*4);
  int* counts = (int*)carve((size_t)NN*4);
  int* rowp   = (int*)carve((size_t)(NN+1)*4);
  int* cursor = (int*)carve((size_t)NN*4);
  u16* bWih   = (u16*)carve((size_t)384*256*2);
  u16* bWhh   = (u16*)carve((size_t)384*128*2);
  u16* bnWih  = (u16*)carve((size_t)384*128*2);
  u16* bnWhh  = (u16*)carve((size_t)384*128*2);
  u16* baW1T  = (u16*)carve((size_t)128*128*2);

  // bf16 conversions (once per launch)
  f2b_kernel<<<2048,256,0,stream>>>(nf_in, nfb, NN*DIM/4);
  f2b_kernel<<<2048,256,0,stream>>>(ef_in, efb, NE*DIM/4);
  f2b_kernel<<<96,256,0,stream>>>(eWih, bWih, 384*256/4);
  f2b_kernel<<<48,256,0,stream>>>(eWhh, bWhh, 384*128/4);
  f2b_kernel<<<48,256,0,stream>>>(nWih, bnWih, 384*128/4);
  f2b_kernel<<<48,256,0,stream>>>(nWhh, bnWhh, 384*128/4);
  transpose128_kernel<<<64,256,0,stream>>>(aW1, baW1T);

  // CSR over dst (constant across iterations)
  zero_kernel<<<(NN+255)/256,256,0,stream>>>(counts, NN);
  hist_kernel<<<(NE+255)/256,256,0,stream>>>(dst, counts, NE);
  scan_kernel<<<1,1024,0,stream>>>(counts, rowp, cursor, NN);
  scatter_kernel<<<(NE+255)/256,256,0,stream>>>(dst, cursor, eids, NE);

  for (int it=0; it<2; ++it){
    const float* nf_cur = (it==0) ? nf_in : nf_out;
    float* efout32 = (it==1) ? ef_out : nullptr;
    edge_kernel<<<NE/128,512,0,stream>>>(src, dst, nfb, efb,
                                         bWih, bWhh, ebih, ebhh,
                                         baW1T, ab1, aW2, ab2, logits, efout32);
    agg_kernel<<<(NN+3)/4,256,0,stream>>>(rowp, eids, logits, efb, aggb);
    node_kernel<<<(NN/16+3)/4,256,0,stream>>>(aggb, nfb, nf_cur, nf_out,
                                              bnWih, bnWhh, nbih, nbhh);
  }
}

// Round 4
// 903.947 us; speedup vs baseline: 2.7387x; 2.0802x over previous
//
#include <hip/hip_runtime.h>

#define NN 50000
#define NE 400000
#define DIM 128

typedef __bf16 bf16x8 __attribute__((ext_vector_type(8)));
typedef float f32x4 __attribute__((ext_vector_type(4)));
typedef unsigned short u16;

#define MFMA16 __builtin_amdgcn_mfma_f32_16x16x32_bf16

__device__ __forceinline__ u16 f2b(float f){ __bf16 b=(__bf16)f; return __builtin_bit_cast(u16,b); }
__device__ __forceinline__ float b2f(u16 h){ unsigned u = ((unsigned)h)<<16; return __builtin_bit_cast(float,u); }
__device__ __forceinline__ float sigm(float x){ return 1.0f/(1.0f+__expf(-x)); }
__device__ __forceinline__ float tanh_(float x){ float e=__expf(2.0f*x); return 1.0f-2.0f/(e+1.0f); }
__device__ __forceinline__ bf16x8 ldb8(const u16* p){ return *reinterpret_cast<const bf16x8*>(p); }

#define GLOAD_LDS(gp, lp) __builtin_amdgcn_global_load_lds( \
    (const __attribute__((address_space(1))) void*)(gp),    \
    (__attribute__((address_space(3))) void*)(lp), 16, 0, 0)

// ---------- utility kernels ----------
__global__ void f2b_kernel(const float* __restrict__ in, u16* __restrict__ out, int n4){
  int i = blockIdx.x*blockDim.x + threadIdx.x;
  int st = gridDim.x*blockDim.x;
  for (; i<n4; i+=st){
    float4 v = reinterpret_cast<const float4*>(in)[i];
    ushort4 o = { f2b(v.x), f2b(v.y), f2b(v.z), f2b(v.w) };
    reinterpret_cast<ushort4*>(out)[i] = o;
  }
}

__global__ void transpose128_kernel(const float* __restrict__ in, u16* __restrict__ out){
  int i = blockIdx.x*blockDim.x + threadIdx.x; // 16384 threads total
  int k = i>>7, n = i&127;
  out[n*128+k] = f2b(in[i]);   // out[n][k] = in[k][n]
}

__global__ void zero_kernel(int* p, int n){
  int i = blockIdx.x*blockDim.x + threadIdx.x; if (i<n) p[i]=0;
}
__global__ void hist_kernel(const int* __restrict__ dst, int* __restrict__ counts, int n){
  int i = blockIdx.x*blockDim.x + threadIdx.x; if (i<n) atomicAdd(&counts[dst[i]],1);
}
__global__ void scan_kernel(const int* __restrict__ counts, int* __restrict__ rowp,
                            int* __restrict__ cursor, int n){
  __shared__ int buf[1024];
  __shared__ int run;
  const int t = threadIdx.x;
  if (t==0) run = 0;
  __syncthreads();
  for (int base=0; base<n; base+=1024){
    int v = (base+t<n) ? counts[base+t] : 0;
    buf[t]=v; __syncthreads();
    for (int off=1; off<1024; off<<=1){
      int x = (t>=off) ? buf[t-off] : 0;
      __syncthreads();
      buf[t]+=x; __syncthreads();
    }
    int incl = buf[t];
    int br = run;
    __syncthreads();
    if (base+t<n){ int ex = br+incl-v; rowp[base+t]=ex; cursor[base+t]=ex; }
    if (t==1023) run = br+incl;
    __syncthreads();
  }
  if (t==0) rowp[n]=run;
}
__global__ void scatter_kernel(const int* __restrict__ dst, int* __restrict__ cursor,
                               int* __restrict__ eids, int n){
  int i = blockIdx.x*blockDim.x + threadIdx.x;
  if (i<n){ int p = atomicAdd(&cursor[dst[i]],1); eids[p]=i; }
}

// ---------- edge GRU + attention MLP (v4) ----------
// 512 thr = 8 waves x 16 edges. Weights LDS-staged per chunk (frag-major, 36KB).
// launch_bounds(512,4): <=128 VGPR so A-frags STAY in registers (v3's (512,8)
// capped at 64 -> compiler rematerialized A-loads every chunk -> 1.8GB FETCH).
// Per-wave 16x128 uef tile in XOR-swizzled LDS (32KB/block) kills the h0 /
// attn-A / writeback global re-reads. LDS 68KB -> 2 blocks/CU, 16 waves/CU.
__global__ __launch_bounds__(512, 4)
void edge_kernel(const int* __restrict__ src, const int* __restrict__ dst,
                 const u16* __restrict__ nfb, u16* __restrict__ efb,
                 const u16* __restrict__ Wih, const u16* __restrict__ Whh,
                 const float* __restrict__ bih, const float* __restrict__ bhh,
                 const u16* __restrict__ aW1T, const float* __restrict__ ab1,
                 const float* __restrict__ aW2, const float* __restrict__ ab2,
                 float* __restrict__ logits, float* __restrict__ ef32out)
{
  __shared__ __align__(16) u16 wbuf[36*512];     // 36 KB staged weights, frag-major
  __shared__ __align__(16) u16 etile[8*16*128];  // 32 KB: per-wave uef tiles, swizzled
  const int wave = threadIdx.x>>6, lane = threadIdx.x&63;
  const int r16 = lane&15, kq = lane>>4;
  const long base = (long)blockIdx.x*128 + wave*16;
  const long e = base + r16;
  char* tb = (char*)(etile + wave*16*DIM);       // this wave's tile (bytes)

  // cooperative staging of chunk c's weight frags (c=8 -> attention weights)
  auto stage = [&](int c){
    if (c < 8){
      for (int f = wave; f < 36; f += 8){
        const u16* g;
        if (f < 24){ const int gt = f>>3, s = f&7;
          g = Wih + (long)(gt*128 + c*16 + r16)*256 + s*32 + kq*8; }
        else { const int q = f-24, gt = q>>2, s = q&3;
          g = Whh + (long)(gt*128 + c*16 + r16)*128 + s*32 + kq*8; }
        GLOAD_LDS(g, wbuf + f*512);
      }
    } else {
      for (int f = wave; f < 32; f += 8){
        const int t = f>>2, s = f&3;
        GLOAD_LDS(aW1T + (long)(t*16 + r16)*128 + s*32 + kq*8, wbuf + f*512);
      }
    }
  };

  // A-fragments, loaded ONCE into registers: gi K=256 (src|dst), gh K=128 (ef)
  const u16* sp = nfb + (long)src[e]*DIM;
  const u16* dp = nfb + (long)dst[e]*DIM;
  const u16* ep = efb + e*DIM;
  bf16x8 ag[8], ae[4];
#pragma unroll
  for (int s=0;s<4;++s){
    ag[s]   = ldb8(sp + s*32 + kq*8);
    ag[s+4] = ldb8(dp + s*32 + kq*8);
    ae[s]   = ldb8(ep + s*32 + kq*8);
  }
  // seed the wave's ef tile in LDS (A-layout rows, XOR-swizzled 16B slots)
#pragma unroll
  for (int s=0;s<4;++s)
    *(uint4*)(tb + r16*256 + ((s*64 + kq*16) ^ ((r16&7)<<4))) = __builtin_bit_cast(uint4, ae[s]);
  stage(0);
  __syncthreads();

  const f32x4 vzero = {0.f,0.f,0.f,0.f};
  const u16* lbase = wbuf + lane*8;   // frag f => lbase + f*512 (u16 units)

#pragma unroll 1
  for (int c=0;c<8;++c){
    const int oc = c*16 + r16;
    const float bir=bih[oc], biz=bih[DIM+oc], bin=bih[2*DIM+oc];
    const float bhr=bhh[oc], bhz=bhh[DIM+oc], bhn=bhh[2*DIM+oc];

    f32x4 ar=vzero, az=vzero, an=vzero, hr=vzero, hz=vzero, hn=vzero;
#pragma unroll
    for (int s=0;s<8;++s){
      ar = MFMA16(ag[s], ldb8(lbase + ( s   )*512), ar,0,0,0);
      az = MFMA16(ag[s], ldb8(lbase + ( 8+s )*512), az,0,0,0);
      an = MFMA16(ag[s], ldb8(lbase + (16+s )*512), an,0,0,0);
    }
#pragma unroll
    for (int s=0;s<4;++s){
      hr = MFMA16(ae[s], ldb8(lbase + (24+s)*512), hr,0,0,0);
      hz = MFMA16(ae[s], ldb8(lbase + (28+s)*512), hz,0,0,0);
      hn = MFMA16(ae[s], ldb8(lbase + (32+s)*512), hn,0,0,0);
    }
    __syncthreads();              // all waves done reading wbuf
    stage(c+1);                   // refill for next chunk (c+1<=8)
    // epilogue overlaps stage latency; h0 from this wave's LDS tile
#pragma unroll
    for (int r=0;r<4;++r){
      const int row = kq*4+r;
      char* slot = tb + row*256 + ((oc*2 - c*32 + c*32) ^ 0); // placeholder no-op
      (void)slot;
      const int boff = row*256 + (((c*32) + r16*2) ^ ((row&7)<<4));
      float h0 = b2f(*(const u16*)(tb + boff));
      float rg = sigm(ar[r]+bir + hr[r]+bhr);
      float zg = sigm(az[r]+biz + hz[r]+bhz);
      float ng = tanh_(an[r]+bin + rg*(hn[r]+bhn));
      float u  = (1.0f-zg)*ng + zg*h0;
      *(u16*)(tb + boff) = f2b(u);
      if (ef32out) ef32out[(base+row)*DIM+oc] = u;
    }
    __syncthreads();              // wbuf refilled
  }

  // ----- attention MLP: aW1T in wbuf; A-frags from this wave's uef tile -----
  bf16x8 ua[4];
#pragma unroll
  for (int s=0;s<4;++s)
    ua[s] = __builtin_bit_cast(bf16x8, *(const uint4*)(tb + r16*256 + ((s*64 + kq*16) ^ ((r16&7)<<4))));
  float part[4] = {0.f,0.f,0.f,0.f};
#pragma unroll 1
  for (int t=0;t<8;++t){
    f32x4 h = vzero;
#pragma unroll
    for (int s=0;s<4;++s)
      h = MFMA16(ua[s], ldb8(lbase + (t*4+s)*512), h,0,0,0);
    const int cc = t*16 + r16;
    const float b1 = ab1[cc], w2 = aW2[cc];
#pragma unroll
    for (int r=0;r<4;++r) part[r] += fmaxf(h[r]+b1, 0.f)*w2;
  }
#pragma unroll
  for (int off=1; off<16; off<<=1){
#pragma unroll
    for (int r=0;r<4;++r) part[r] += __shfl_xor(part[r], off, 64);
  }
  if (r16==0){
    const float b2v = ab2[0];
#pragma unroll
    for (int r=0;r<4;++r) logits[base + kq*4 + r] = part[r] + b2v;
  }

  // coalesced writeback: wave tile (LDS) -> efb, 16B per lane x4
#pragma unroll
  for (int i2=0;i2<4;++i2){
    const int idx = i2*64 + lane;
    const int row = idx>>4, slot = idx&15;
    uint4 val = *(const uint4*)(tb + row*256 + ((slot*16) ^ ((row&7)<<4)));
    *(uint4*)(efb + (base+row)*DIM + slot*8) = val;
  }
}

// ---------- softmax + weighted aggregation (CSR, one wave per node, bf16 uef) ----------
__global__ __launch_bounds__(256)
void agg_kernel(const int* __restrict__ rowp, const int* __restrict__ eids,
                const float* __restrict__ logits, const u16* __restrict__ uefb,
                u16* __restrict__ aggb)
{
  const int wave = threadIdx.x>>6, lane = threadIdx.x&63;
  const int v = blockIdx.x*4 + wave;
  if (v>=NN) return;
  const int p0 = rowp[v], deg = rowp[v+1]-p0;
  float ax=0.f, ay=0.f;
  if (deg>0){
    float mx = -__builtin_inff();
    for (int i=lane; i<deg; i+=64) mx = fmaxf(mx, logits[eids[p0+i]]);
#pragma unroll
    for (int off=32; off; off>>=1) mx = fmaxf(mx, __shfl_xor(mx, off, 64));
    float ss = 0.f;
    for (int i=lane; i<deg; i+=64) ss += __expf(logits[eids[p0+i]] - mx);
#pragma unroll
    for (int off=32; off; off>>=1) ss += __shfl_xor(ss, off, 64);
    const float inv = 1.0f/ss;
    int i = 0;
    for (; i+2<=deg; i+=2){
      const int e0 = eids[p0+i], e1 = eids[p0+i+1];
      const float l0 = logits[e0], l1 = logits[e1];
      const unsigned q0 = *reinterpret_cast<const unsigned*>(uefb + (long)e0*DIM + lane*2);
      const unsigned q1 = *reinterpret_cast<const unsigned*>(uefb + (long)e1*DIM + lane*2);
      const float a0 = __expf(l0-mx)*inv, a1 = __expf(l1-mx)*inv;
      ax += a0*b2f((u16)q0) + a1*b2f((u16)q1);
      ay += a0*b2f((u16)(q0>>16)) + a1*b2f((u16)(q1>>16));
    }
    if (i<deg){
      const int e0 = eids[p0+i];
      const float a0 = __expf(logits[e0]-mx)*inv;
      const unsigned q0 = *reinterpret_cast<const unsigned*>(uefb + (long)e0*DIM + lane*2);
      ax += a0*b2f((u16)q0);
      ay += a0*b2f((u16)(q0>>16));
    }
  }
  unsigned pack = (unsigned)f2b(ax) | ((unsigned)f2b(ay)<<16);
  *reinterpret_cast<unsigned*>(aggb + (long)v*DIM + lane*2) = pack;
}

// ---------- node GRU (v2: LDS-staged weights, 8 waves x 16 nodes) ----------
__global__ __launch_bounds__(512, 4)
void node_kernel(const u16* __restrict__ aggb, u16* __restrict__ nfb,
                 const float* nf32, float* unf32,            // may alias (in-place iter 2)
                 const u16* __restrict__ Wih, const u16* __restrict__ Whh,
                 const float* __restrict__ bih, const float* __restrict__ bhh)
{
  __shared__ __align__(16) u16 wbuf[24*512];   // 24 KB, frag-major
  const int wave = threadIdx.x>>6, lane = threadIdx.x&63;
  const int r16 = lane&15, kq = lane>>4;
  const long tbase = (long)blockIdx.x*128 + wave*16;
  const long v = tbase + r16;
  const long vcl = (v < NN) ? v : (NN-1);

  auto stage = [&](int c){
    if (c >= 8) return;
    for (int f = wave; f < 24; f += 8){
      const u16* g;
      if (f < 12){ const int gt = f>>2, s = f&3;
        g = Wih + (long)(gt*128 + c*16 + r16)*128 + s*32 + kq*8; }
      else { const int q = f-12, gt = q>>2, s = q&3;
        g = Whh + (long)(gt*128 + c*16 + r16)*128 + s*32 + kq*8; }
      GLOAD_LDS(g, wbuf + f*512);
    }
  };

  bf16x8 xa[4], ha[4];
#pragma unroll
  for (int s=0;s<4;++s){
    xa[s] = ldb8(aggb + vcl*DIM + s*32 + kq*8);
    ha[s] = ldb8(nfb  + vcl*DIM + s*32 + kq*8);
  }
  stage(0);
  __syncthreads();

  const f32x4 vzero = {0.f,0.f,0.f,0.f};
  const u16* lbase = wbuf + lane*8;

#pragma unroll 1
  for (int c=0;c<8;++c){
    const int oc = c*16 + r16;
    const float bir=bih[oc], biz=bih[DIM+oc], bin=bih[2*DIM+oc];
    const float bhr=bhh[oc], bhz=bhh[DIM+oc], bhn=bhh[2*DIM+oc];
    float h0p[4];
#pragma unroll
    for (int r=0;r<4;++r){
      const long rr = tbase + kq*4 + r;
      h0p[r] = (rr < NN) ? nf32[rr*DIM+oc] : 0.f;
    }
    f32x4 ar=vzero, az=vzero, an=vzero, hr=vzero, hz=vzero, hn=vzero;
#pragma unroll
    for (int s=0;s<4;++s){
      ar=MFMA16(xa[s], ldb8(lbase + ( s   )*512), ar,0,0,0);
      az=MFMA16(xa[s], ldb8(lbase + ( 4+s)*512), az,0,0,0);
      an=MFMA16(xa[s], ldb8(lbase + ( 8+s)*512), an,0,0,0);
      hr=MFMA16(ha[s], ldb8(lbase + (12+s)*512), hr,0,0,0);
      hz=MFMA16(ha[s], ldb8(lbase + (16+s)*512), hz,0,0,0);
      hn=MFMA16(ha[s], ldb8(lbase + (20+s)*512), hn,0,0,0);
    }
    __syncthreads();
    stage(c+1);
#pragma unroll
    for (int r=0;r<4;++r){
      const long rr = tbase + kq*4 + r;
      if (rr < NN){
        float rg = sigm(ar[r]+bir + hr[r]+bhr);
        float zg = sigm(az[r]+biz + hz[r]+bhz);
        float ng = tanh_(an[r]+bin + rg*(hn[r]+bhn));
        float u  = (1.0f-zg)*ng + zg*h0p[r];
        unf32[rr*DIM+oc] = u;
        nfb[rr*DIM+oc] = f2b(u);   // safe: nfb reads preloaded before loop
      }
    }
    __syncthreads();
  }
}

extern "C" void kernel_launch(void* const* d_in, const int* in_sizes, int n_in,
                              void* d_out, int out_size, void* d_ws, size_t ws_size,
                              hipStream_t stream)
{
  const float* nf_in = (const float*)d_in[0];
  const float* ef_in = (const float*)d_in[1];
  const int*   src   = (const int*)d_in[2];
  const int*   dst   = (const int*)d_in[3];
  const float* eWih  = (const float*)d_in[4];
  const float* eWhh  = (const float*)d_in[5];
  const float* ebih  = (const float*)d_in[6];
  const float* ebhh  = (const float*)d_in[7];
  const float* nWih  = (const float*)d_in[8];
  const float* nWhh  = (const float*)d_in[9];
  const float* nbih  = (const float*)d_in[10];
  const float* nbhh  = (const float*)d_in[11];
  const float* aW1   = (const float*)d_in[12];
  const float* ab1   = (const float*)d_in[13];
  const float* aW2   = (const float*)d_in[14];
  const float* ab2   = (const float*)d_in[15];

  float* nf_out = (float*)d_out;
  float* ef_out = nf_out + (size_t)NN*DIM;

  // workspace carve
  char* p = (char*)d_ws;
  auto carve = [&](size_t bytes)->void*{ void* r = (void*)p; p += (bytes + 255) & ~(size_t)255; return r; };
  u16* efb    = (u16*)carve((size_t)NE*DIM*2);
  u16* nfb    = (u16*)carve((size_t)NN*DIM*2);
  u16* aggb   = (u16*)carve((size_t)NN*DIM*2);
  float* logits = (float*)carve((size_t)NE*4);
  int* eids   = (int*)carve((size_t)NE*4);
  int* counts = (int*)carve((size_t)NN*4);
  int* rowp   = (int*)carve((size_t)(NN+1)*4);
  int* cursor = (int*)carve((size_t)NN*4);
  u16* bWih   = (u16*)carve((size_t)384*256*2);
  u16* bWhh   = (u16*)carve((size_t)384*128*2);
  u16* bnWih  = (u16*)carve((size_t)384*128*2);
  u16* bnWhh  = (u16*)carve((size_t)384*128*2);
  u16* baW1T  = (u16*)carve((size_t)128*128*2);

  // bf16 conversions (once per launch)
  f2b_kernel<<<2048,256,0,stream>>>(nf_in, nfb, NN*DIM/4);
  f2b_kernel<<<2048,256,0,stream>>>(ef_in, efb, NE*DIM/4);
  f2b_kernel<<<96,256,0,stream>>>(eWih, bWih, 384*256/4);
  f2b_kernel<<<48,256,0,stream>>>(eWhh, bWhh, 384*128/4);
  f2b_kernel<<<48,256,0,stream>>>(nWih, bnWih, 384*128/4);
  f2b_kernel<<<48,256,0,stream>>>(nWhh, bnWhh, 384*128/4);
  transpose128_kernel<<<64,256,0,stream>>>(aW1, baW1T);

  // CSR over dst (constant across iterations)
  zero_kernel<<<(NN+255)/256,256,0,stream>>>(counts, NN);
  hist_kernel<<<(NE+255)/256,256,0,stream>>>(dst, counts, NE);
  scan_kernel<<<1,1024,0,stream>>>(counts, rowp, cursor, NN);
  scatter_kernel<<<(NE+255)/256,256,0,stream>>>(dst, cursor, eids, NE);

  for (int it=0; it<2; ++it){
    const float* nf_cur = (it==0) ? nf_in : nf_out;
    float* efout32 = (it==1) ? ef_out : nullptr;
    edge_kernel<<<NE/128,512,0,stream>>>(src, dst, nfb, efb,
                                         bWih, bWhh, ebih, ebhh,
                                         baW1T, ab1, aW2, ab2, logits, efout32);
    agg_kernel<<<(NN+3)/4,256,0,stream>>>(rowp, eids, logits, efb, aggb);
    node_kernel<<<(NN+127)/128,512,0,stream>>>(aggb, nfb, nf_cur, nf_out,
                                               bnWih, bnWhh, nbih, nbhh);
  }
}